// Round 1
// baseline (2627.018 us; speedup 1.0000x reference)
//
#include <hip/hip_runtime.h>
#include <math.h>

#define N_NODES 50000
#define N_EDGES 1600000

__device__ __forceinline__ float rl(float v, int srclane){
  return __int_as_float(__builtin_amdgcn_readlane(__float_as_int(v), srclane));
}

// ---------------- graph setup ----------------

__global__ void k_count(const int* __restrict__ rowE, const int* __restrict__ colE,
                        int* __restrict__ rowcnt, int* __restrict__ degcnt){
  int e = blockIdx.x*256 + threadIdx.x;
  if(e < N_EDGES){
    atomicAdd(&rowcnt[rowE[e]], 1);
    atomicAdd(&degcnt[colE[e]], 1);
  }
}

__global__ void k_dinv(const int* __restrict__ degcnt, float* __restrict__ dinv){
  int i = blockIdx.x*256 + threadIdx.x;
  if(i < N_NODES) dinv[i] = rsqrtf((float)(degcnt[i] + 1));  // +1 self-loop; always > 0
}

__global__ void k_scan(const int* __restrict__ rowcnt, int* __restrict__ row_ptr,
                       int* __restrict__ row_fill){
  __shared__ int part[1024];
  int t = threadIdx.x;
  const int chunk = (N_NODES + 1023) / 1024;
  int st = t*chunk, s = 0;
  for(int i=0;i<chunk;i++){ int idx=st+i; if(idx<N_NODES) s += rowcnt[idx]; }
  part[t] = s; __syncthreads();
  for(int off=1; off<1024; off<<=1){
    int v = (t>=off) ? part[t-off] : 0;
    __syncthreads();
    part[t] += v;
    __syncthreads();
  }
  int run = (t==0) ? 0 : part[t-1];
  for(int i=0;i<chunk;i++){
    int idx=st+i;
    if(idx<N_NODES){ row_ptr[idx]=run; row_fill[idx]=run; run += rowcnt[idx]; }
  }
  if(t==0) row_ptr[N_NODES] = part[1023];
}

__global__ void k_scatter(const int* __restrict__ rowE, const int* __restrict__ colE,
                          const float* __restrict__ dinv, int* __restrict__ row_fill,
                          int* __restrict__ csr_col, float* __restrict__ csr_val){
  int e = blockIdx.x*256 + threadIdx.x;
  if(e < N_EDGES){
    int r = rowE[e], c = colE[e];
    int pos = atomicAdd(&row_fill[r], 1);
    csr_col[pos] = c;
    csr_val[pos] = dinv[r]*dinv[c];
  }
}

// ---------------- dense 64x64 GEMMs (readlane broadcast) ----------------
// block = 256 (4 waves); each wave handles 4 rows; lane = output column.
// lane l holds x flat floats [row0*64 + 4l, +4): row = row0 + l/16, cols 4*(l%16)..+3

__global__ __launch_bounds__(256) void k_lin0(const float* __restrict__ x, const float* __restrict__ W,
                                              const float* __restrict__ b, float* __restrict__ h){
  __shared__ float Wl[4096];
  int t = threadIdx.x;
  for(int i=t;i<4096;i+=256) Wl[i] = W[i];
  __syncthreads();
  int wave = t>>6, lane = t&63;
  int row0 = blockIdx.x*16 + wave*4;
  float4 xq = ((const float4*)(x + (size_t)row0*64))[lane];
  float a0=0,a1=0,a2=0,a3=0;
  #pragma unroll
  for(int k=0;k<64;k++){
    float w = Wl[k*64+lane];
    float comp = ((k&3)==0)?xq.x:((k&3)==1)?xq.y:((k&3)==2)?xq.z:xq.w;
    a0 += rl(comp,      (k>>2)) * w;
    a1 += rl(comp, 16 + (k>>2)) * w;
    a2 += rl(comp, 32 + (k>>2)) * w;
    a3 += rl(comp, 48 + (k>>2)) * w;
  }
  float bb = b[lane];
  h[(size_t)(row0+0)*64+lane] = fmaxf(a0+bb, 0.f);
  h[(size_t)(row0+1)*64+lane] = fmaxf(a1+bb, 0.f);
  h[(size_t)(row0+2)*64+lane] = fmaxf(a2+bb, 0.f);
  h[(size_t)(row0+3)*64+lane] = fmaxf(a3+bb, 0.f);
}

// A = h @ W1[:64], B = h @ W1[64:], one pass over h
__global__ __launch_bounds__(256) void k_ab(const float* __restrict__ h, const float* __restrict__ W1,
                                            float* __restrict__ A, float* __restrict__ B){
  __shared__ float Wa[4096];
  __shared__ float Wb[4096];
  int t = threadIdx.x;
  for(int i=t;i<4096;i+=256){ Wa[i] = W1[i]; Wb[i] = W1[4096+i]; }
  __syncthreads();
  int wave = t>>6, lane = t&63;
  int row0 = blockIdx.x*16 + wave*4;
  float4 xq = ((const float4*)(h + (size_t)row0*64))[lane];
  float a0=0,a1=0,a2=0,a3=0,b0=0,b1=0,b2=0,b3=0;
  #pragma unroll
  for(int k=0;k<64;k++){
    float wa = Wa[k*64+lane], wb = Wb[k*64+lane];
    float comp = ((k&3)==0)?xq.x:((k&3)==1)?xq.y:((k&3)==2)?xq.z:xq.w;
    float s0 = rl(comp,      (k>>2));
    float s1 = rl(comp, 16 + (k>>2));
    float s2 = rl(comp, 32 + (k>>2));
    float s3 = rl(comp, 48 + (k>>2));
    a0 += s0*wa; a1 += s1*wa; a2 += s2*wa; a3 += s3*wa;
    b0 += s0*wb; b1 += s1*wb; b2 += s2*wb; b3 += s3*wb;
  }
  A[(size_t)(row0+0)*64+lane]=a0; A[(size_t)(row0+1)*64+lane]=a1;
  A[(size_t)(row0+2)*64+lane]=a2; A[(size_t)(row0+3)*64+lane]=a3;
  B[(size_t)(row0+0)*64+lane]=b0; B[(size_t)(row0+1)*64+lane]=b1;
  B[(size_t)(row0+2)*64+lane]=b2; B[(size_t)(row0+3)*64+lane]=b3;
}

// ---------------- fused GCN2 layer: SpMM + initial-residual mix + identity-mapped dense ----------------
// one wave per 4 nodes; lane = feature. Gathers h[col]*val over CSR row, adds self-loop,
// mixes with h0, then dense mix@Ws via readlane broadcast, relu.
__global__ __launch_bounds__(256) void k_layer(const float* __restrict__ hin, const float* __restrict__ h0,
                          const int* __restrict__ row_ptr, const int* __restrict__ csr_col,
                          const float* __restrict__ csr_val, const float* __restrict__ dinv,
                          const float* __restrict__ Wsl, float beta, float* __restrict__ hout){
  __shared__ float Wl[4096];
  int t = threadIdx.x;
  for(int i=t;i<4096;i+=256) Wl[i] = Wsl[i];
  __syncthreads();
  int wave = t>>6, lane = t&63;
  float w[64];
  #pragma unroll
  for(int k=0;k<64;k++) w[k] = Wl[k*64+lane];
  int i0 = blockIdx.x*16 + wave*4;
  for(int r=0;r<4;r++){
    int i = i0 + r;
    float di = dinv[i];
    float acc = di*di*hin[(size_t)i*64+lane];   // self-loop
    int e0 = row_ptr[i], e1 = row_ptr[i+1];
    for(int e=e0;e<e1;e++){
      int c = csr_col[e];
      float v = csr_val[e];
      acc += v * hin[(size_t)c*64+lane];
    }
    float mix = 0.9f*acc + 0.1f*h0[(size_t)i*64+lane];
    float dm = 0.f;
    #pragma unroll
    for(int k=0;k<64;k++) dm += rl(mix,k) * w[k];
    hout[(size_t)i*64+lane] = fmaxf((1.f-beta)*mix + beta*dm, 0.f);
  }
}

// ---------------- per-edge MLP: z = A[src]+B[dst]+b1 -> LN -> relu -> @W2 + b2 ----------------
// 16 lanes per edge; lane l holds z[4l..4l+3]
__global__ __launch_bounds__(256) void k_edge(const float* __restrict__ A, const float* __restrict__ B,
                         const int* __restrict__ srcE, const int* __restrict__ dstE,
                         const float* __restrict__ b1v, const float* __restrict__ lng,
                         const float* __restrict__ lnb, const float* __restrict__ W2,
                         const float* __restrict__ b2v, float* __restrict__ out){
  int t = threadIdx.x;
  int grp = t>>4, l = t&15;
  int e = blockIdx.x*16 + grp;
  if(e >= N_EDGES) return;
  // W2 rows 4l..4l+3 (40 consecutive floats) into registers
  float w2r[40];
  const float4* W2v = (const float4*)W2;
  #pragma unroll
  for(int m=0;m<10;m++){
    float4 q = W2v[l*10+m];
    w2r[4*m]=q.x; w2r[4*m+1]=q.y; w2r[4*m+2]=q.z; w2r[4*m+3]=q.w;
  }
  int s = srcE[e], d = dstE[e];
  float4 a  = ((const float4*)A)[(size_t)s*16 + l];
  float4 b  = ((const float4*)B)[(size_t)d*16 + l];
  float4 bl = ((const float4*)b1v)[l];
  float z0=a.x+b.x+bl.x, z1=a.y+b.y+bl.y, z2=a.z+b.z+bl.z, z3=a.w+b.w+bl.w;
  float s1=z0+z1+z2+z3;
  float s2=z0*z0+z1*z1+z2*z2+z3*z3;
  #pragma unroll
  for(int m=1;m<16;m<<=1){ s1 += __shfl_xor(s1,m,16); s2 += __shfl_xor(s2,m,16); }
  float mu  = s1*(1.f/64.f);
  float var = s2*(1.f/64.f) - mu*mu;
  float rs  = rsqrtf(var + 1e-5f);
  float4 g  = ((const float4*)lng)[l];
  float4 bb = ((const float4*)lnb)[l];
  z0 = fmaxf((z0-mu)*rs*g.x + bb.x, 0.f);
  z1 = fmaxf((z1-mu)*rs*g.y + bb.y, 0.f);
  z2 = fmaxf((z2-mu)*rs*g.z + bb.z, 0.f);
  z3 = fmaxf((z3-mu)*rs*g.w + bb.w, 0.f);
  float p[10];
  #pragma unroll
  for(int c=0;c<10;c++) p[c] = z0*w2r[c] + z1*w2r[10+c] + z2*w2r[20+c] + z3*w2r[30+c];
  #pragma unroll
  for(int c=0;c<10;c++){
    #pragma unroll
    for(int m=1;m<16;m<<=1) p[c] += __shfl_xor(p[c],m,16);
  }
  float ov = p[0];
  #pragma unroll
  for(int c=1;c<10;c++) ov = (l==c) ? p[c] : ov;
  if(l<10) out[(size_t)e*10 + l] = ov + b2v[l];
}

// ---------------- launch ----------------

extern "C" void kernel_launch(void* const* d_in, const int* in_sizes, int n_in,
                              void* d_out, int out_size, void* d_ws, size_t ws_size,
                              hipStream_t stream){
  const float* x     = (const float*)d_in[0];
  const float* W_lin = (const float*)d_in[1];
  const float* b_lin = (const float*)d_in[2];
  const float* Ws    = (const float*)d_in[3];
  const float* W1    = (const float*)d_in[4];
  const float* b1    = (const float*)d_in[5];
  const float* ln_g  = (const float*)d_in[6];
  const float* ln_b  = (const float*)d_in[7];
  const float* W2    = (const float*)d_in[8];
  const float* b2    = (const float*)d_in[9];
  const int*   eidx  = (const int*)d_in[10];
  const int*   rowE  = eidx;
  const int*   colE  = eidx + N_EDGES;
  float* out = (float*)d_out;

  char* ws = (char*)d_ws;
  size_t o = 0;
  auto alloc = [&](size_t bytes)->char*{ char* p = ws + o; o = (o + bytes + 255) & ~(size_t)255; return p; };
  int*   rowcnt  = (int*)  alloc((size_t)N_NODES*4);
  int*   degcnt  = (int*)  alloc((size_t)N_NODES*4);
  int*   row_ptr = (int*)  alloc((size_t)(N_NODES+1)*4);
  int*   row_fill= (int*)  alloc((size_t)N_NODES*4);
  float* dinv    = (float*)alloc((size_t)N_NODES*4);
  int*   csr_col = (int*)  alloc((size_t)N_EDGES*4);
  float* csr_val = (float*)alloc((size_t)N_EDGES*4);
  float* h0      = (float*)alloc((size_t)N_NODES*64*4);
  float* hA      = (float*)alloc((size_t)N_NODES*64*4);
  float* hB      = (float*)alloc((size_t)N_NODES*64*4);

  hipMemsetAsync(rowcnt, 0, (size_t)N_NODES*4, stream);
  hipMemsetAsync(degcnt, 0, (size_t)N_NODES*4, stream);

  k_count  <<<(N_EDGES+255)/256, 256, 0, stream>>>(rowE, colE, rowcnt, degcnt);
  k_dinv   <<<(N_NODES+255)/256, 256, 0, stream>>>(degcnt, dinv);
  k_scan   <<<1, 1024, 0, stream>>>(rowcnt, row_ptr, row_fill);
  k_scatter<<<(N_EDGES+255)/256, 256, 0, stream>>>(rowE, colE, dinv, row_fill, csr_col, csr_val);

  k_lin0<<<N_NODES/16, 256, 0, stream>>>(x, W_lin, b_lin, h0);

  const float* hin = h0;
  float* bufs[2] = {hA, hB};
  for(int L=0; L<8; L++){
    float beta = logf(0.5f/(float)(L+1) + 1.0f);
    float* hout = bufs[L&1];
    k_layer<<<N_NODES/16, 256, 0, stream>>>(hin, h0, row_ptr, csr_col, csr_val, dinv,
                                            Ws + (size_t)L*4096, beta, hout);
    hin = hout;
  }
  // final h is hB (layer 7 writes bufs[1]); hA and h0 are now free -> reuse for A, B
  float* Abuf = hA;
  float* Bbuf = h0;
  k_ab<<<N_NODES/16, 256, 0, stream>>>(hB, W1, Abuf, Bbuf);
  k_edge<<<N_EDGES/16, 256, 0, stream>>>(Abuf, Bbuf, rowE, colE, b1, ln_g, ln_b, W2, b2, out);
}

// Round 2
// 1516.758 us; speedup vs baseline: 1.7320x; 1.7320x over previous
//
#include <hip/hip_runtime.h>
#include <hip/hip_fp16.h>
#include <math.h>

#define N_NODES 50000
#define N_EDGES 1600000

__device__ __forceinline__ float rl(float v, int srclane){
  return __int_as_float(__builtin_amdgcn_readlane(__float_as_int(v), srclane));
}

// ---------------- graph setup ----------------

__global__ void k_count(const int* __restrict__ rowE, const int* __restrict__ colE,
                        int* __restrict__ rowcnt, int* __restrict__ degcnt){
  int e = blockIdx.x*256 + threadIdx.x;
  if(e < N_EDGES){
    atomicAdd(&rowcnt[rowE[e]], 1);
    atomicAdd(&degcnt[colE[e]], 1);
  }
}

__global__ void k_dinv(const int* __restrict__ degcnt, float* __restrict__ dinv){
  int i = blockIdx.x*256 + threadIdx.x;
  if(i < N_NODES) dinv[i] = rsqrtf((float)(degcnt[i] + 1));  // +1 self-loop; always > 0
}

__global__ void k_scan(const int* __restrict__ rowcnt, int* __restrict__ row_ptr,
                       int* __restrict__ row_fill){
  __shared__ int part[1024];
  int t = threadIdx.x;
  const int chunk = (N_NODES + 1023) / 1024;
  int st = t*chunk, s = 0;
  for(int i=0;i<chunk;i++){ int idx=st+i; if(idx<N_NODES) s += rowcnt[idx]; }
  part[t] = s; __syncthreads();
  for(int off=1; off<1024; off<<=1){
    int v = (t>=off) ? part[t-off] : 0;
    __syncthreads();
    part[t] += v;
    __syncthreads();
  }
  int run = (t==0) ? 0 : part[t-1];
  for(int i=0;i<chunk;i++){
    int idx=st+i;
    if(idx<N_NODES){ row_ptr[idx]=run; row_fill[idx]=run; run += rowcnt[idx]; }
  }
  if(t==0) row_ptr[N_NODES] = part[1023];
}

__global__ void k_scatter(const int* __restrict__ rowE, const int* __restrict__ colE,
                          const float* __restrict__ dinv, int* __restrict__ row_fill,
                          int* __restrict__ csr_col, float* __restrict__ csr_val){
  int e = blockIdx.x*256 + threadIdx.x;
  if(e < N_EDGES){
    int r = rowE[e], c = colE[e];
    int pos = atomicAdd(&row_fill[r], 1);
    csr_col[pos] = c;
    csr_val[pos] = dinv[r]*dinv[c];
  }
}

// ---------------- dense 64x64 GEMMs (readlane broadcast) ----------------

__global__ __launch_bounds__(256) void k_lin0(const float* __restrict__ x, const float* __restrict__ W,
                                              const float* __restrict__ b, __half* __restrict__ h){
  __shared__ float Wl[4096];
  int t = threadIdx.x;
  for(int i=t;i<4096;i+=256) Wl[i] = W[i];
  __syncthreads();
  int wave = t>>6, lane = t&63;
  int row0 = blockIdx.x*16 + wave*4;
  float4 xq = ((const float4*)(x + (size_t)row0*64))[lane];
  float a0=0,a1=0,a2=0,a3=0;
  #pragma unroll
  for(int k=0;k<64;k++){
    float w = Wl[k*64+lane];
    float comp = ((k&3)==0)?xq.x:((k&3)==1)?xq.y:((k&3)==2)?xq.z:xq.w;
    a0 += rl(comp,      (k>>2)) * w;
    a1 += rl(comp, 16 + (k>>2)) * w;
    a2 += rl(comp, 32 + (k>>2)) * w;
    a3 += rl(comp, 48 + (k>>2)) * w;
  }
  float bb = b[lane];
  h[(size_t)(row0+0)*64+lane] = __float2half(fmaxf(a0+bb, 0.f));
  h[(size_t)(row0+1)*64+lane] = __float2half(fmaxf(a1+bb, 0.f));
  h[(size_t)(row0+2)*64+lane] = __float2half(fmaxf(a2+bb, 0.f));
  h[(size_t)(row0+3)*64+lane] = __float2half(fmaxf(a3+bb, 0.f));
}

// A = h @ W1[:64], B = h @ W1[64:], one pass over h (fp16 in, fp16 out)
__global__ __launch_bounds__(256) void k_ab(const __half* __restrict__ h, const float* __restrict__ W1,
                                            __half* __restrict__ A, __half* __restrict__ B){
  __shared__ float Wa[4096];
  __shared__ float Wb[4096];
  int t = threadIdx.x;
  for(int i=t;i<4096;i+=256){ Wa[i] = W1[i]; Wb[i] = W1[4096+i]; }
  __syncthreads();
  int wave = t>>6, lane = t&63;
  int row0 = blockIdx.x*16 + wave*4;
  // lane holds 4 consecutive fp16 features (8 B)
  const __half2* hp = (const __half2*)(h + (size_t)row0*64);
  __half2 p01 = hp[2*lane], p23 = hp[2*lane+1];
  float2 f01 = __half22float2(p01), f23 = __half22float2(p23);
  float4 xq = make_float4(f01.x, f01.y, f23.x, f23.y);
  float a0=0,a1=0,a2=0,a3=0,b0=0,b1=0,b2=0,b3=0;
  #pragma unroll
  for(int k=0;k<64;k++){
    float wa = Wa[k*64+lane], wb = Wb[k*64+lane];
    float comp = ((k&3)==0)?xq.x:((k&3)==1)?xq.y:((k&3)==2)?xq.z:xq.w;
    float s0 = rl(comp,      (k>>2));
    float s1 = rl(comp, 16 + (k>>2));
    float s2 = rl(comp, 32 + (k>>2));
    float s3 = rl(comp, 48 + (k>>2));
    a0 += s0*wa; a1 += s1*wa; a2 += s2*wa; a3 += s3*wa;
    b0 += s0*wb; b1 += s1*wb; b2 += s2*wb; b3 += s3*wb;
  }
  A[(size_t)(row0+0)*64+lane]=__float2half(a0); A[(size_t)(row0+1)*64+lane]=__float2half(a1);
  A[(size_t)(row0+2)*64+lane]=__float2half(a2); A[(size_t)(row0+3)*64+lane]=__float2half(a3);
  B[(size_t)(row0+0)*64+lane]=__float2half(b0); B[(size_t)(row0+1)*64+lane]=__float2half(b1);
  B[(size_t)(row0+2)*64+lane]=__float2half(b2); B[(size_t)(row0+3)*64+lane]=__float2half(b3);
}

// ---------------- fused GCN2 layer ----------------
// one wave per 4 nodes; lane = feature. fp16 gathers (128 B/row), fp32 accumulate.
__global__ __launch_bounds__(256) void k_layer(const __half* __restrict__ hin, const __half* __restrict__ h0,
                          const int* __restrict__ row_ptr, const int* __restrict__ csr_col,
                          const float* __restrict__ csr_val, const float* __restrict__ dinv,
                          const float* __restrict__ Wsl, float beta, __half* __restrict__ hout){
  __shared__ float Wl[4096];
  int t = threadIdx.x;
  for(int i=t;i<4096;i+=256) Wl[i] = Wsl[i];
  __syncthreads();
  int wave = t>>6, lane = t&63;
  float w[64];
  #pragma unroll
  for(int k=0;k<64;k++) w[k] = Wl[k*64+lane];
  int i0 = blockIdx.x*16 + wave*4;
  for(int r=0;r<4;r++){
    int i = i0 + r;
    float di = dinv[i];
    float acc = di*di*__half2float(hin[(size_t)i*64+lane]);   // self-loop
    int e = row_ptr[i], e1 = row_ptr[i+1];
    // unrolled x4: batch 4 outstanding gathers for latency hiding
    for(; e+4<=e1; e+=4){
      int c0 = csr_col[e+0], c1 = csr_col[e+1], c2 = csr_col[e+2], c3 = csr_col[e+3];
      float v0 = csr_val[e+0], v1 = csr_val[e+1], v2 = csr_val[e+2], v3 = csr_val[e+3];
      float g0 = __half2float(hin[(size_t)c0*64+lane]);
      float g1 = __half2float(hin[(size_t)c1*64+lane]);
      float g2 = __half2float(hin[(size_t)c2*64+lane]);
      float g3 = __half2float(hin[(size_t)c3*64+lane]);
      acc += v0*g0; acc += v1*g1; acc += v2*g2; acc += v3*g3;
    }
    for(; e<e1; e++){
      acc += csr_val[e] * __half2float(hin[(size_t)csr_col[e]*64+lane]);
    }
    float mix = 0.9f*acc + 0.1f*__half2float(h0[(size_t)i*64+lane]);
    float dm = 0.f;
    #pragma unroll
    for(int k=0;k<64;k++) dm += rl(mix,k) * w[k];
    hout[(size_t)i*64+lane] = __float2half(fmaxf((1.f-beta)*mix + beta*dm, 0.f));
  }
}

// ---------------- per-edge MLP ----------------
// 16 lanes per edge; lane l holds z[4l..4l+3]; A/B fp16 (8 B/lane gathers)
__global__ __launch_bounds__(256) void k_edge(const __half* __restrict__ A, const __half* __restrict__ B,
                         const int* __restrict__ srcE, const int* __restrict__ dstE,
                         const float* __restrict__ b1v, const float* __restrict__ lng,
                         const float* __restrict__ lnb, const float* __restrict__ W2,
                         const float* __restrict__ b2v, float* __restrict__ out){
  int t = threadIdx.x;
  int grp = t>>4, l = t&15;
  int e = blockIdx.x*16 + grp;
  if(e >= N_EDGES) return;
  float w2r[40];
  const float4* W2v = (const float4*)W2;
  #pragma unroll
  for(int m=0;m<10;m++){
    float4 q = W2v[l*10+m];
    w2r[4*m]=q.x; w2r[4*m+1]=q.y; w2r[4*m+2]=q.z; w2r[4*m+3]=q.w;
  }
  int s = srcE[e], d = dstE[e];
  const __half2* Ap = (const __half2*)(A + (size_t)s*64);
  const __half2* Bp = (const __half2*)(B + (size_t)d*64);
  __half2 a01 = Ap[2*l], a23 = Ap[2*l+1];
  __half2 b01 = Bp[2*l], b23 = Bp[2*l+1];
  float2 fa01 = __half22float2(a01), fa23 = __half22float2(a23);
  float2 fb01 = __half22float2(b01), fb23 = __half22float2(b23);
  float4 bl = ((const float4*)b1v)[l];
  float z0=fa01.x+fb01.x+bl.x, z1=fa01.y+fb01.y+bl.y;
  float z2=fa23.x+fb23.x+bl.z, z3=fa23.y+fb23.y+bl.w;
  float s1=z0+z1+z2+z3;
  float s2=z0*z0+z1*z1+z2*z2+z3*z3;
  #pragma unroll
  for(int m=1;m<16;m<<=1){ s1 += __shfl_xor(s1,m,16); s2 += __shfl_xor(s2,m,16); }
  float mu  = s1*(1.f/64.f);
  float var = s2*(1.f/64.f) - mu*mu;
  float rs  = rsqrtf(var + 1e-5f);
  float4 g  = ((const float4*)lng)[l];
  float4 bb = ((const float4*)lnb)[l];
  z0 = fmaxf((z0-mu)*rs*g.x + bb.x, 0.f);
  z1 = fmaxf((z1-mu)*rs*g.y + bb.y, 0.f);
  z2 = fmaxf((z2-mu)*rs*g.z + bb.z, 0.f);
  z3 = fmaxf((z3-mu)*rs*g.w + bb.w, 0.f);
  float p[10];
  #pragma unroll
  for(int c=0;c<10;c++) p[c] = z0*w2r[c] + z1*w2r[10+c] + z2*w2r[20+c] + z3*w2r[30+c];
  #pragma unroll
  for(int c=0;c<10;c++){
    #pragma unroll
    for(int m=1;m<16;m<<=1) p[c] += __shfl_xor(p[c],m,16);
  }
  float ov = p[0];
  #pragma unroll
  for(int c=1;c<10;c++) ov = (l==c) ? p[c] : ov;
  if(l<10) out[(size_t)e*10 + l] = ov + b2v[l];
}

// ---------------- launch ----------------

extern "C" void kernel_launch(void* const* d_in, const int* in_sizes, int n_in,
                              void* d_out, int out_size, void* d_ws, size_t ws_size,
                              hipStream_t stream){
  const float* x     = (const float*)d_in[0];
  const float* W_lin = (const float*)d_in[1];
  const float* b_lin = (const float*)d_in[2];
  const float* Ws    = (const float*)d_in[3];
  const float* W1    = (const float*)d_in[4];
  const float* b1    = (const float*)d_in[5];
  const float* ln_g  = (const float*)d_in[6];
  const float* ln_b  = (const float*)d_in[7];
  const float* W2    = (const float*)d_in[8];
  const float* b2    = (const float*)d_in[9];
  const int*   eidx  = (const int*)d_in[10];
  const int*   rowE  = eidx;
  const int*   colE  = eidx + N_EDGES;
  float* out = (float*)d_out;

  char* ws = (char*)d_ws;
  size_t o = 0;
  auto alloc = [&](size_t bytes)->char*{ char* p = ws + o; o = (o + bytes + 255) & ~(size_t)255; return p; };
  int*   rowcnt  = (int*)  alloc((size_t)N_NODES*4);
  int*   degcnt  = (int*)  alloc((size_t)N_NODES*4);
  int*   row_ptr = (int*)  alloc((size_t)(N_NODES+1)*4);
  int*   row_fill= (int*)  alloc((size_t)N_NODES*4);
  float* dinv    = (float*)alloc((size_t)N_NODES*4);
  int*   csr_col = (int*)  alloc((size_t)N_EDGES*4);
  float* csr_val = (float*)alloc((size_t)N_EDGES*4);
  __half* h0     = (__half*)alloc((size_t)N_NODES*64*2);
  __half* hA     = (__half*)alloc((size_t)N_NODES*64*2);
  __half* hB     = (__half*)alloc((size_t)N_NODES*64*2);
  __half* Abuf   = (__half*)alloc((size_t)N_NODES*64*2);
  __half* Bbuf   = (__half*)alloc((size_t)N_NODES*64*2);

  hipMemsetAsync(rowcnt, 0, (size_t)N_NODES*4, stream);
  hipMemsetAsync(degcnt, 0, (size_t)N_NODES*4, stream);

  k_count  <<<(N_EDGES+255)/256, 256, 0, stream>>>(rowE, colE, rowcnt, degcnt);
  k_dinv   <<<(N_NODES+255)/256, 256, 0, stream>>>(degcnt, dinv);
  k_scan   <<<1, 1024, 0, stream>>>(rowcnt, row_ptr, row_fill);
  k_scatter<<<(N_EDGES+255)/256, 256, 0, stream>>>(rowE, colE, dinv, row_fill, csr_col, csr_val);

  k_lin0<<<N_NODES/16, 256, 0, stream>>>(x, W_lin, b_lin, h0);

  const __half* hin = h0;
  __half* bufs[2] = {hA, hB};
  for(int L=0; L<8; L++){
    float beta = logf(0.5f/(float)(L+1) + 1.0f);
    __half* hout = bufs[L&1];
    k_layer<<<N_NODES/16, 256, 0, stream>>>(hin, h0, row_ptr, csr_col, csr_val, dinv,
                                            Ws + (size_t)L*4096, beta, hout);
    hin = hout;
  }
  // final h is hB (layer 7 writes bufs[1])
  k_ab<<<N_NODES/16, 256, 0, stream>>>(hB, W1, Abuf, Bbuf);
  k_edge<<<N_EDGES/16, 256, 0, stream>>>(Abuf, Bbuf, rowE, colE, b1, ln_g, ln_b, W2, b2, out);
}

// Round 3
// 1409.493 us; speedup vs baseline: 1.8638x; 1.0761x over previous
//
#include <hip/hip_runtime.h>
#include <hip/hip_fp16.h>
#include <math.h>

#define N_NODES 50000
#define N_EDGES 1600000

using half8  = __attribute__((ext_vector_type(8))) _Float16;
using float4v = __attribute__((ext_vector_type(4))) float;

__device__ __forceinline__ float rl(float v, int srclane){
  return __int_as_float(__builtin_amdgcn_readlane(__float_as_int(v), srclane));
}
__device__ __forceinline__ float rfl_f(float v){
  return __uint_as_float(__builtin_amdgcn_readfirstlane(__float_as_uint(v)));
}

// ---------------- graph setup ----------------

__global__ void k_count(const int* __restrict__ rowE, const int* __restrict__ colE,
                        int* __restrict__ rowcnt, int* __restrict__ degcnt){
  int e = blockIdx.x*256 + threadIdx.x;
  if(e < N_EDGES){
    atomicAdd(&rowcnt[rowE[e]], 1);
    atomicAdd(&degcnt[colE[e]], 1);
  }
}

__global__ void k_dinv(const int* __restrict__ degcnt, float* __restrict__ dinv){
  int i = blockIdx.x*256 + threadIdx.x;
  if(i < N_NODES) dinv[i] = rsqrtf((float)(degcnt[i] + 1));  // +1 self-loop; always > 0
}

__global__ void k_scan(const int* __restrict__ rowcnt, int* __restrict__ row_ptr,
                       int* __restrict__ row_fill){
  __shared__ int part[1024];
  int t = threadIdx.x;
  const int chunk = (N_NODES + 1023) / 1024;
  int st = t*chunk, s = 0;
  for(int i=0;i<chunk;i++){ int idx=st+i; if(idx<N_NODES) s += rowcnt[idx]; }
  part[t] = s; __syncthreads();
  for(int off=1; off<1024; off<<=1){
    int v = (t>=off) ? part[t-off] : 0;
    __syncthreads();
    part[t] += v;
    __syncthreads();
  }
  int run = (t==0) ? 0 : part[t-1];
  for(int i=0;i<chunk;i++){
    int idx=st+i;
    if(idx<N_NODES){ row_ptr[idx]=run; row_fill[idx]=run; run += rowcnt[idx]; }
  }
  if(t==0) row_ptr[N_NODES] = part[1023];
}

__global__ void k_scatter(const int* __restrict__ rowE, const int* __restrict__ colE,
                          const float* __restrict__ dinv, int* __restrict__ row_fill,
                          int* __restrict__ csr_col, float* __restrict__ csr_val){
  int e = blockIdx.x*256 + threadIdx.x;
  if(e < N_EDGES){
    int r = rowE[e], c = colE[e];
    int pos = atomicAdd(&row_fill[r], 1);
    csr_col[pos] = c;
    csr_val[pos] = dinv[r]*dinv[c];
  }
}

// ---------------- lin0: x @ W_lin + b, relu -> fp16 (readlane broadcast) ----------------

__global__ __launch_bounds__(256) void k_lin0(const float* __restrict__ x, const float* __restrict__ W,
                                              const float* __restrict__ b, __half* __restrict__ h){
  __shared__ float Wl[4096];
  int t = threadIdx.x;
  for(int i=t;i<4096;i+=256) Wl[i] = W[i];
  __syncthreads();
  int wave = t>>6, lane = t&63;
  int row0 = blockIdx.x*16 + wave*4;
  float4 xq = ((const float4*)(x + (size_t)row0*64))[lane];
  float a0=0,a1=0,a2=0,a3=0;
  #pragma unroll
  for(int k=0;k<64;k++){
    float w = Wl[k*64+lane];
    float comp = ((k&3)==0)?xq.x:((k&3)==1)?xq.y:((k&3)==2)?xq.z:xq.w;
    a0 += rl(comp,      (k>>2)) * w;
    a1 += rl(comp, 16 + (k>>2)) * w;
    a2 += rl(comp, 32 + (k>>2)) * w;
    a3 += rl(comp, 48 + (k>>2)) * w;
  }
  float bb = b[lane];
  h[(size_t)(row0+0)*64+lane] = __float2half(fmaxf(a0+bb, 0.f));
  h[(size_t)(row0+1)*64+lane] = __float2half(fmaxf(a1+bb, 0.f));
  h[(size_t)(row0+2)*64+lane] = __float2half(fmaxf(a2+bb, 0.f));
  h[(size_t)(row0+3)*64+lane] = __float2half(fmaxf(a3+bb, 0.f));
}

// A = h @ W1[:64], B = h @ W1[64:], one pass over h (fp16 in, fp16 out)
__global__ __launch_bounds__(256) void k_ab(const __half* __restrict__ h, const float* __restrict__ W1,
                                            __half* __restrict__ A, __half* __restrict__ B){
  __shared__ float Wa[4096];
  __shared__ float Wb[4096];
  int t = threadIdx.x;
  for(int i=t;i<4096;i+=256){ Wa[i] = W1[i]; Wb[i] = W1[4096+i]; }
  __syncthreads();
  int wave = t>>6, lane = t&63;
  int row0 = blockIdx.x*16 + wave*4;
  const __half2* hp = (const __half2*)(h + (size_t)row0*64);
  __half2 p01 = hp[2*lane], p23 = hp[2*lane+1];
  float2 f01 = __half22float2(p01), f23 = __half22float2(p23);
  float4 xq = make_float4(f01.x, f01.y, f23.x, f23.y);
  float a0=0,a1=0,a2=0,a3=0,b0=0,b1=0,b2=0,b3=0;
  #pragma unroll
  for(int k=0;k<64;k++){
    float wa = Wa[k*64+lane], wb = Wb[k*64+lane];
    float comp = ((k&3)==0)?xq.x:((k&3)==1)?xq.y:((k&3)==2)?xq.z:xq.w;
    float s0 = rl(comp,      (k>>2));
    float s1 = rl(comp, 16 + (k>>2));
    float s2 = rl(comp, 32 + (k>>2));
    float s3 = rl(comp, 48 + (k>>2));
    a0 += s0*wa; a1 += s1*wa; a2 += s2*wa; a3 += s3*wa;
    b0 += s0*wb; b1 += s1*wb; b2 += s2*wb; b3 += s3*wb;
  }
  A[(size_t)(row0+0)*64+lane]=__float2half(a0); A[(size_t)(row0+1)*64+lane]=__float2half(a1);
  A[(size_t)(row0+2)*64+lane]=__float2half(a2); A[(size_t)(row0+3)*64+lane]=__float2half(a3);
  B[(size_t)(row0+0)*64+lane]=__float2half(b0); B[(size_t)(row0+1)*64+lane]=__float2half(b1);
  B[(size_t)(row0+2)*64+lane]=__float2half(b2); B[(size_t)(row0+3)*64+lane]=__float2half(b3);
}

// ---------------- fused GCN2 layer v2 ----------------
// Block = 16 nodes (4 waves x 4 nodes). Per wave: scalarized CSR SpMM (lane = feature),
// mix -> fp16 LDS tile. Then hout = relu(mix @ M), M = beta*Ws + (1-beta)*I, via
// 2x mfma_f32_16x16x32_f16 per wave (wave w owns output cols 16w..16w+15).
__global__ __launch_bounds__(256) void k_layer(const __half* __restrict__ hin, const __half* __restrict__ h0,
                          const int* __restrict__ row_ptr, const int* __restrict__ csr_col,
                          const float* __restrict__ csr_val, const float* __restrict__ dinv,
                          const float* __restrict__ Wsl, float beta, __half* __restrict__ hout){
  __shared__ __align__(16) _Float16 tile[16*72];   // stride 72 halves (144 B, 16B-aligned)
  int t = threadIdx.x, wave = t>>6, lane = t&63;
  int quad = lane>>4, l15 = lane&15;

  // B-fragments: M[k][n] for n-tile of this wave, built once (fp16)
  half8 bfrag0, bfrag1;
  int n = 16*wave + l15;
  #pragma unroll
  for(int j=0;j<8;j++){
    int k0 = quad*8 + j;
    int k1 = 32 + quad*8 + j;
    float v0 = beta*Wsl[k0*64+n] + ((k0==n)?(1.f-beta):0.f);
    float v1 = beta*Wsl[k1*64+n] + ((k1==n)?(1.f-beta):0.f);
    bfrag0[j] = (_Float16)v0;
    bfrag1[j] = (_Float16)v1;
  }

  int i0 = blockIdx.x*16;
  for(int r=0;r<4;r++){
    int il = 4*wave + r;
    int i = i0 + il;
    float di = dinv[i];
    float acc = di*di*__half2float(hin[(size_t)i*64+lane]);   // self-loop
    int e = row_ptr[i], e1 = row_ptr[i+1];
    for(; e+4<=e1; e+=4){
      int   c0 = __builtin_amdgcn_readfirstlane(csr_col[e+0]);
      int   c1 = __builtin_amdgcn_readfirstlane(csr_col[e+1]);
      int   c2 = __builtin_amdgcn_readfirstlane(csr_col[e+2]);
      int   c3 = __builtin_amdgcn_readfirstlane(csr_col[e+3]);
      float v0 = rfl_f(csr_val[e+0]);
      float v1 = rfl_f(csr_val[e+1]);
      float v2 = rfl_f(csr_val[e+2]);
      float v3 = rfl_f(csr_val[e+3]);
      float g0 = __half2float(hin[(size_t)c0*64+lane]);
      float g1 = __half2float(hin[(size_t)c1*64+lane]);
      float g2 = __half2float(hin[(size_t)c2*64+lane]);
      float g3 = __half2float(hin[(size_t)c3*64+lane]);
      acc += v0*g0; acc += v1*g1; acc += v2*g2; acc += v3*g3;
    }
    for(; e<e1; e++){
      int   c = __builtin_amdgcn_readfirstlane(csr_col[e]);
      float v = rfl_f(csr_val[e]);
      acc += v * __half2float(hin[(size_t)c*64+lane]);
    }
    float mix = 0.9f*acc + 0.1f*__half2float(h0[(size_t)i*64+lane]);
    tile[il*72 + lane] = (_Float16)mix;
  }
  __syncthreads();

  // A-frag: lane holds mix[row=l15][k=quad*8+j (+32c)]; D: row=quad*4+r, col=l15 (n-tile)
  float4v acc4 = {0.f,0.f,0.f,0.f};
  half8 afrag0 = *(const half8*)&tile[l15*72 + quad*8];
  half8 afrag1 = *(const half8*)&tile[l15*72 + quad*8 + 32];
  acc4 = __builtin_amdgcn_mfma_f32_16x16x32_f16(afrag0, bfrag0, acc4, 0,0,0);
  acc4 = __builtin_amdgcn_mfma_f32_16x16x32_f16(afrag1, bfrag1, acc4, 0,0,0);
  #pragma unroll
  for(int r=0;r<4;r++){
    int row = quad*4 + r;
    hout[(size_t)(i0+row)*64 + n] = __float2half(fmaxf(acc4[r], 0.f));
  }
}

// ---------------- per-edge MLP ----------------
// 16 lanes per edge; lane l holds z[4l..4l+3]; A/B fp16 (8 B/lane gathers)
__global__ __launch_bounds__(256) void k_edge(const __half* __restrict__ A, const __half* __restrict__ B,
                         const int* __restrict__ srcE, const int* __restrict__ dstE,
                         const float* __restrict__ b1v, const float* __restrict__ lng,
                         const float* __restrict__ lnb, const float* __restrict__ W2,
                         const float* __restrict__ b2v, float* __restrict__ out){
  int t = threadIdx.x;
  int grp = t>>4, l = t&15;
  int e = blockIdx.x*16 + grp;
  if(e >= N_EDGES) return;
  float w2r[40];
  const float4* W2v = (const float4*)W2;
  #pragma unroll
  for(int m=0;m<10;m++){
    float4 q = W2v[l*10+m];
    w2r[4*m]=q.x; w2r[4*m+1]=q.y; w2r[4*m+2]=q.z; w2r[4*m+3]=q.w;
  }
  int s = srcE[e], d = dstE[e];
  const __half2* Ap = (const __half2*)(A + (size_t)s*64);
  const __half2* Bp = (const __half2*)(B + (size_t)d*64);
  __half2 a01 = Ap[2*l], a23 = Ap[2*l+1];
  __half2 b01 = Bp[2*l], b23 = Bp[2*l+1];
  float2 fa01 = __half22float2(a01), fa23 = __half22float2(a23);
  float2 fb01 = __half22float2(b01), fb23 = __half22float2(b23);
  float4 bl = ((const float4*)b1v)[l];
  float z0=fa01.x+fb01.x+bl.x, z1=fa01.y+fb01.y+bl.y;
  float z2=fa23.x+fb23.x+bl.z, z3=fa23.y+fb23.y+bl.w;
  float s1=z0+z1+z2+z3;
  float s2=z0*z0+z1*z1+z2*z2+z3*z3;
  #pragma unroll
  for(int m=1;m<16;m<<=1){ s1 += __shfl_xor(s1,m,16); s2 += __shfl_xor(s2,m,16); }
  float mu  = s1*(1.f/64.f);
  float var = s2*(1.f/64.f) - mu*mu;
  float rs  = rsqrtf(var + 1e-5f);
  float4 g  = ((const float4*)lng)[l];
  float4 bb = ((const float4*)lnb)[l];
  z0 = fmaxf((z0-mu)*rs*g.x + bb.x, 0.f);
  z1 = fmaxf((z1-mu)*rs*g.y + bb.y, 0.f);
  z2 = fmaxf((z2-mu)*rs*g.z + bb.z, 0.f);
  z3 = fmaxf((z3-mu)*rs*g.w + bb.w, 0.f);
  float p[10];
  #pragma unroll
  for(int c=0;c<10;c++) p[c] = z0*w2r[c] + z1*w2r[10+c] + z2*w2r[20+c] + z3*w2r[30+c];
  #pragma unroll
  for(int c=0;c<10;c++){
    #pragma unroll
    for(int m=1;m<16;m<<=1) p[c] += __shfl_xor(p[c],m,16);
  }
  float ov = p[0];
  #pragma unroll
  for(int c=1;c<10;c++) ov = (l==c) ? p[c] : ov;
  if(l<10) out[(size_t)e*10 + l] = ov + b2v[l];
}

// ---------------- launch ----------------

extern "C" void kernel_launch(void* const* d_in, const int* in_sizes, int n_in,
                              void* d_out, int out_size, void* d_ws, size_t ws_size,
                              hipStream_t stream){
  const float* x     = (const float*)d_in[0];
  const float* W_lin = (const float*)d_in[1];
  const float* b_lin = (const float*)d_in[2];
  const float* Ws    = (const float*)d_in[3];
  const float* W1    = (const float*)d_in[4];
  const float* b1    = (const float*)d_in[5];
  const float* ln_g  = (const float*)d_in[6];
  const float* ln_b  = (const float*)d_in[7];
  const float* W2    = (const float*)d_in[8];
  const float* b2    = (const float*)d_in[9];
  const int*   eidx  = (const int*)d_in[10];
  const int*   rowE  = eidx;
  const int*   colE  = eidx + N_EDGES;
  float* out = (float*)d_out;

  char* ws = (char*)d_ws;
  size_t o = 0;
  auto alloc = [&](size_t bytes)->char*{ char* p = ws + o; o = (o + bytes + 255) & ~(size_t)255; return p; };
  int*   rowcnt  = (int*)  alloc((size_t)N_NODES*4);
  int*   degcnt  = (int*)  alloc((size_t)N_NODES*4);
  int*   row_ptr = (int*)  alloc((size_t)(N_NODES+1)*4);
  int*   row_fill= (int*)  alloc((size_t)N_NODES*4);
  float* dinv    = (float*)alloc((size_t)N_NODES*4);
  int*   csr_col = (int*)  alloc((size_t)N_EDGES*4);
  float* csr_val = (float*)alloc((size_t)N_EDGES*4);
  __half* h0     = (__half*)alloc((size_t)N_NODES*64*2);
  __half* hA     = (__half*)alloc((size_t)N_NODES*64*2);
  __half* hB     = (__half*)alloc((size_t)N_NODES*64*2);
  __half* Abuf   = (__half*)alloc((size_t)N_NODES*64*2);
  __half* Bbuf   = (__half*)alloc((size_t)N_NODES*64*2);

  hipMemsetAsync(rowcnt, 0, (size_t)N_NODES*4, stream);
  hipMemsetAsync(degcnt, 0, (size_t)N_NODES*4, stream);

  k_count  <<<(N_EDGES+255)/256, 256, 0, stream>>>(rowE, colE, rowcnt, degcnt);
  k_dinv   <<<(N_NODES+255)/256, 256, 0, stream>>>(degcnt, dinv);
  k_scan   <<<1, 1024, 0, stream>>>(rowcnt, row_ptr, row_fill);
  k_scatter<<<(N_EDGES+255)/256, 256, 0, stream>>>(rowE, colE, dinv, row_fill, csr_col, csr_val);

  k_lin0<<<N_NODES/16, 256, 0, stream>>>(x, W_lin, b_lin, h0);

  const __half* hin = h0;
  __half* bufs[2] = {hA, hB};
  for(int L=0; L<8; L++){
    float beta = logf(0.5f/(float)(L+1) + 1.0f);
    __half* hout = bufs[L&1];
    k_layer<<<(N_NODES+15)/16, 256, 0, stream>>>(hin, h0, row_ptr, csr_col, csr_val, dinv,
                                                 Ws + (size_t)L*4096, beta, hout);
    hin = hout;
  }
  // final h is hB (layer 7 writes bufs[1])
  k_ab<<<N_NODES/16, 256, 0, stream>>>(hB, W1, Abuf, Bbuf);
  k_edge<<<N_EDGES/16, 256, 0, stream>>>(Abuf, Bbuf, rowE, colE, b1, ln_g, ln_b, W2, b2, out);
}

// Round 4
// 977.266 us; speedup vs baseline: 2.6881x; 1.4423x over previous
//
#include <hip/hip_runtime.h>
#include <hip/hip_fp16.h>
#include <math.h>

#define N_NODES 50000
#define N_EDGES 1600000

using half8  = __attribute__((ext_vector_type(8))) _Float16;
using float4v = __attribute__((ext_vector_type(4))) float;

__device__ __forceinline__ float rl(float v, int srclane){
  return __int_as_float(__builtin_amdgcn_readlane(__float_as_int(v), srclane));
}

// ---------------- graph setup ----------------

__global__ void k_count(const int* __restrict__ rowE, const int* __restrict__ colE,
                        int* __restrict__ rowcnt, int* __restrict__ degcnt){
  int e = blockIdx.x*256 + threadIdx.x;
  if(e < N_EDGES){
    atomicAdd(&rowcnt[rowE[e]], 1);
    atomicAdd(&degcnt[colE[e]], 1);
  }
}

__global__ void k_dinv(const int* __restrict__ degcnt, float* __restrict__ dinv){
  int i = blockIdx.x*256 + threadIdx.x;
  if(i < N_NODES) dinv[i] = rsqrtf((float)(degcnt[i] + 1));  // +1 self-loop; always > 0
}

__global__ void k_scan(const int* __restrict__ rowcnt, int* __restrict__ row_ptr,
                       int* __restrict__ row_fill){
  __shared__ int part[1024];
  int t = threadIdx.x;
  const int chunk = (N_NODES + 1023) / 1024;
  int st = t*chunk, s = 0;
  for(int i=0;i<chunk;i++){ int idx=st+i; if(idx<N_NODES) s += rowcnt[idx]; }
  part[t] = s; __syncthreads();
  for(int off=1; off<1024; off<<=1){
    int v = (t>=off) ? part[t-off] : 0;
    __syncthreads();
    part[t] += v;
    __syncthreads();
  }
  int run = (t==0) ? 0 : part[t-1];
  for(int i=0;i<chunk;i++){
    int idx=st+i;
    if(idx<N_NODES){ row_ptr[idx]=run; row_fill[idx]=run; run += rowcnt[idx]; }
  }
  if(t==0) row_ptr[N_NODES] = part[1023];
}

__global__ void k_scatter(const int* __restrict__ rowE, const int* __restrict__ colE,
                          const float* __restrict__ dinv, int* __restrict__ row_fill,
                          int* __restrict__ csr_col, float* __restrict__ csr_val){
  int e = blockIdx.x*256 + threadIdx.x;
  if(e < N_EDGES){
    int r = rowE[e], c = colE[e];
    int pos = atomicAdd(&row_fill[r], 1);
    csr_col[pos] = c;
    csr_val[pos] = dinv[r]*dinv[c];
  }
}

// ---------------- lin0: x @ W_lin + b, relu -> fp16 (readlane broadcast) ----------------

__global__ __launch_bounds__(256) void k_lin0(const float* __restrict__ x, const float* __restrict__ W,
                                              const float* __restrict__ b, __half* __restrict__ h){
  __shared__ float Wl[4096];
  int t = threadIdx.x;
  for(int i=t;i<4096;i+=256) Wl[i] = W[i];
  __syncthreads();
  int wave = t>>6, lane = t&63;
  int row0 = blockIdx.x*16 + wave*4;
  float4 xq = ((const float4*)(x + (size_t)row0*64))[lane];
  float a0=0,a1=0,a2=0,a3=0;
  #pragma unroll
  for(int k=0;k<64;k++){
    float w = Wl[k*64+lane];
    float comp = ((k&3)==0)?xq.x:((k&3)==1)?xq.y:((k&3)==2)?xq.z:xq.w;
    a0 += rl(comp,      (k>>2)) * w;
    a1 += rl(comp, 16 + (k>>2)) * w;
    a2 += rl(comp, 32 + (k>>2)) * w;
    a3 += rl(comp, 48 + (k>>2)) * w;
  }
  float bb = b[lane];
  h[(size_t)(row0+0)*64+lane] = __float2half(fmaxf(a0+bb, 0.f));
  h[(size_t)(row0+1)*64+lane] = __float2half(fmaxf(a1+bb, 0.f));
  h[(size_t)(row0+2)*64+lane] = __float2half(fmaxf(a2+bb, 0.f));
  h[(size_t)(row0+3)*64+lane] = __float2half(fmaxf(a3+bb, 0.f));
}

// A = h @ W1[:64], B = h @ W1[64:], one pass over h (fp16 in, fp16 out)
__global__ __launch_bounds__(256) void k_ab(const __half* __restrict__ h, const float* __restrict__ W1,
                                            __half* __restrict__ A, __half* __restrict__ B){
  __shared__ float Wa[4096];
  __shared__ float Wb[4096];
  int t = threadIdx.x;
  for(int i=t;i<4096;i+=256){ Wa[i] = W1[i]; Wb[i] = W1[4096+i]; }
  __syncthreads();
  int wave = t>>6, lane = t&63;
  int row0 = blockIdx.x*16 + wave*4;
  const __half2* hp = (const __half2*)(h + (size_t)row0*64);
  __half2 p01 = hp[2*lane], p23 = hp[2*lane+1];
  float2 f01 = __half22float2(p01), f23 = __half22float2(p23);
  float4 xq = make_float4(f01.x, f01.y, f23.x, f23.y);
  float a0=0,a1=0,a2=0,a3=0,b0=0,b1=0,b2=0,b3=0;
  #pragma unroll
  for(int k=0;k<64;k++){
    float wa = Wa[k*64+lane], wb = Wb[k*64+lane];
    float comp = ((k&3)==0)?xq.x:((k&3)==1)?xq.y:((k&3)==2)?xq.z:xq.w;
    float s0 = rl(comp,      (k>>2));
    float s1 = rl(comp, 16 + (k>>2));
    float s2 = rl(comp, 32 + (k>>2));
    float s3 = rl(comp, 48 + (k>>2));
    a0 += s0*wa; a1 += s1*wa; a2 += s2*wa; a3 += s3*wa;
    b0 += s0*wb; b1 += s1*wb; b2 += s2*wb; b3 += s3*wb;
  }
  A[(size_t)(row0+0)*64+lane]=__float2half(a0); A[(size_t)(row0+1)*64+lane]=__float2half(a1);
  A[(size_t)(row0+2)*64+lane]=__float2half(a2); A[(size_t)(row0+3)*64+lane]=__float2half(a3);
  B[(size_t)(row0+0)*64+lane]=__float2half(b0); B[(size_t)(row0+1)*64+lane]=__float2half(b1);
  B[(size_t)(row0+2)*64+lane]=__float2half(b2); B[(size_t)(row0+3)*64+lane]=__float2half(b3);
}

// ---------------- fused GCN2 layer v3 ----------------
// Block = 16 nodes (4 waves x 4 nodes). Per node: coalesced 64-edge col/val block load
// (lane = edge), then readlane-driven gathers issued 8 deep. mix -> fp16 LDS tile,
// hout = relu(mix @ M), M = beta*Ws + (1-beta)*I via 2x mfma per wave.
__global__ __launch_bounds__(256) void k_layer(const __half* __restrict__ hin, const __half* __restrict__ h0,
                          const int* __restrict__ row_ptr, const int* __restrict__ csr_col,
                          const float* __restrict__ csr_val, const float* __restrict__ dinv,
                          const float* __restrict__ Wsl, float beta, __half* __restrict__ hout){
  __shared__ __align__(16) _Float16 tile[16*72];
  int t = threadIdx.x, wave = t>>6, lane = t&63;
  int quad = lane>>4, l15 = lane&15;

  // B-fragments: M[k][n] for this wave's n-tile
  half8 bfrag0, bfrag1;
  int n = 16*wave + l15;
  #pragma unroll
  for(int j=0;j<8;j++){
    int k0 = quad*8 + j;
    int k1 = 32 + quad*8 + j;
    float v0 = beta*Wsl[k0*64+n] + ((k0==n)?(1.f-beta):0.f);
    float v1 = beta*Wsl[k1*64+n] + ((k1==n)?(1.f-beta):0.f);
    bfrag0[j] = (_Float16)v0;
    bfrag1[j] = (_Float16)v1;
  }

  int i0 = blockIdx.x*16;
  for(int r=0;r<4;r++){
    int il = 4*wave + r;
    int i = i0 + il;
    float di = dinv[i];
    float acc = di*di*__half2float(hin[(size_t)i*64+lane]);   // self-loop
    int e0 = row_ptr[i], e1 = row_ptr[i+1];
    for(int base=e0; base<e1; base+=64){
      int idx = base + lane;
      bool ok = idx < e1;
      int   cl = ok ? csr_col[idx] : 0;
      float vl = ok ? csr_val[idx] : 0.f;
      int cnt = min(64, e1-base);
      int j = 0;
      for(; j+8<=cnt; j+=8){
        float g[8], vv[8];
        #pragma unroll
        for(int u=0;u<8;u++){
          int c = __builtin_amdgcn_readlane(cl, j+u);
          vv[u] = rl(vl, j+u);
          g[u]  = __half2float(hin[(size_t)c*64+lane]);
        }
        #pragma unroll
        for(int u=0;u<8;u++) acc += vv[u]*g[u];
      }
      for(; j<cnt; j++){
        int   c = __builtin_amdgcn_readlane(cl, j);
        float v = rl(vl, j);
        acc += v * __half2float(hin[(size_t)c*64+lane]);
      }
    }
    float mix = 0.9f*acc + 0.1f*__half2float(h0[(size_t)i*64+lane]);
    tile[il*72 + lane] = (_Float16)mix;
  }
  __syncthreads();

  float4v acc4 = {0.f,0.f,0.f,0.f};
  half8 afrag0 = *(const half8*)&tile[l15*72 + quad*8];
  half8 afrag1 = *(const half8*)&tile[l15*72 + quad*8 + 32];
  acc4 = __builtin_amdgcn_mfma_f32_16x16x32_f16(afrag0, bfrag0, acc4, 0,0,0);
  acc4 = __builtin_amdgcn_mfma_f32_16x16x32_f16(afrag1, bfrag1, acc4, 0,0,0);
  #pragma unroll
  for(int r=0;r<4;r++){
    int row = quad*4 + r;
    hout[(size_t)(i0+row)*64 + n] = __float2half(fmaxf(acc4[r], 0.f));
  }
}

// ---------------- per-edge MLP v3: one wave = 16 edges, MFMA for z@W2 ----------------
// lane: l15 = edge within group (also MFMA row/col), quad = feature chunk.
// z row (64 feats) split: frag0 = k[quad*8..+8), frag1 = k[32+quad*8..+8).
__global__ __launch_bounds__(256) void k_edge(const __half* __restrict__ A, const __half* __restrict__ B,
                         const int* __restrict__ srcE, const int* __restrict__ dstE,
                         const float* __restrict__ b1v, const float* __restrict__ lng,
                         const float* __restrict__ lnb, const float* __restrict__ W2,
                         const float* __restrict__ b2v, float* __restrict__ out){
  int t = threadIdx.x, wave = t>>6, lane = t&63;
  int l15 = lane&15, quad = lane>>4;
  int eb = blockIdx.x*64 + wave*16;
  int e  = eb + l15;
  int s = srcE[e], d = dstE[e];
  half8 a0 = *(const half8*)(A + (size_t)s*64 + quad*8);
  half8 a1 = *(const half8*)(A + (size_t)s*64 + 32 + quad*8);
  half8 g0 = *(const half8*)(B + (size_t)d*64 + quad*8);
  half8 g1 = *(const half8*)(B + (size_t)d*64 + 32 + quad*8);
  float z0[8], z1[8];
  float s1 = 0.f, s2 = 0.f;
  #pragma unroll
  for(int j=0;j<8;j++){
    float za = (float)a0[j] + (float)g0[j] + b1v[quad*8+j];
    float zb = (float)a1[j] + (float)g1[j] + b1v[32+quad*8+j];
    z0[j]=za; z1[j]=zb;
    s1 += za + zb;
    s2 += za*za + zb*zb;
  }
  s1 += __shfl_xor(s1,16,64); s1 += __shfl_xor(s1,32,64);
  s2 += __shfl_xor(s2,16,64); s2 += __shfl_xor(s2,32,64);
  float mu  = s1*(1.f/64.f);
  float var = s2*(1.f/64.f) - mu*mu;
  float rs  = rsqrtf(var + 1e-5f);
  half8 af0, af1;
  #pragma unroll
  for(int j=0;j<8;j++){
    float na = fmaxf((z0[j]-mu)*rs*lng[quad*8+j]    + lnb[quad*8+j],    0.f);
    float nb = fmaxf((z1[j]-mu)*rs*lng[32+quad*8+j] + lnb[32+quad*8+j], 0.f);
    af0[j] = (_Float16)na;
    af1[j] = (_Float16)nb;
  }
  half8 bf0, bf1;
  #pragma unroll
  for(int j=0;j<8;j++){
    float w0 = (l15<10) ? W2[(quad*8+j)*10 + l15]    : 0.f;
    float w1 = (l15<10) ? W2[(32+quad*8+j)*10 + l15] : 0.f;
    bf0[j] = (_Float16)w0;
    bf1[j] = (_Float16)w1;
  }
  float4v acc = {0.f,0.f,0.f,0.f};
  acc = __builtin_amdgcn_mfma_f32_16x16x32_f16(af0, bf0, acc, 0,0,0);
  acc = __builtin_amdgcn_mfma_f32_16x16x32_f16(af1, bf1, acc, 0,0,0);
  if(l15 < 10){
    float bias = b2v[l15];
    #pragma unroll
    for(int r=0;r<4;r++){
      out[(size_t)(eb + quad*4 + r)*10 + l15] = acc[r] + bias;
    }
  }
}

// ---------------- launch ----------------

extern "C" void kernel_launch(void* const* d_in, const int* in_sizes, int n_in,
                              void* d_out, int out_size, void* d_ws, size_t ws_size,
                              hipStream_t stream){
  const float* x     = (const float*)d_in[0];
  const float* W_lin = (const float*)d_in[1];
  const float* b_lin = (const float*)d_in[2];
  const float* Ws    = (const float*)d_in[3];
  const float* W1    = (const float*)d_in[4];
  const float* b1    = (const float*)d_in[5];
  const float* ln_g  = (const float*)d_in[6];
  const float* ln_b  = (const float*)d_in[7];
  const float* W2    = (const float*)d_in[8];
  const float* b2    = (const float*)d_in[9];
  const int*   eidx  = (const int*)d_in[10];
  const int*   rowE  = eidx;
  const int*   colE  = eidx + N_EDGES;
  float* out = (float*)d_out;

  char* ws = (char*)d_ws;
  size_t o = 0;
  auto alloc = [&](size_t bytes)->char*{ char* p = ws + o; o = (o + bytes + 255) & ~(size_t)255; return p; };
  int*   rowcnt  = (int*)  alloc((size_t)N_NODES*4);
  int*   degcnt  = (int*)  alloc((size_t)N_NODES*4);
  int*   row_ptr = (int*)  alloc((size_t)(N_NODES+1)*4);
  int*   row_fill= (int*)  alloc((size_t)N_NODES*4);
  float* dinv    = (float*)alloc((size_t)N_NODES*4);
  int*   csr_col = (int*)  alloc((size_t)N_EDGES*4);
  float* csr_val = (float*)alloc((size_t)N_EDGES*4);
  __half* h0     = (__half*)alloc((size_t)N_NODES*64*2);
  __half* hA     = (__half*)alloc((size_t)N_NODES*64*2);
  __half* hB     = (__half*)alloc((size_t)N_NODES*64*2);
  __half* Abuf   = (__half*)alloc((size_t)N_NODES*64*2);
  __half* Bbuf   = (__half*)alloc((size_t)N_NODES*64*2);

  hipMemsetAsync(rowcnt, 0, (size_t)N_NODES*4, stream);
  hipMemsetAsync(degcnt, 0, (size_t)N_NODES*4, stream);

  k_count  <<<(N_EDGES+255)/256, 256, 0, stream>>>(rowE, colE, rowcnt, degcnt);
  k_dinv   <<<(N_NODES+255)/256, 256, 0, stream>>>(degcnt, dinv);
  k_scan   <<<1, 1024, 0, stream>>>(rowcnt, row_ptr, row_fill);
  k_scatter<<<(N_EDGES+255)/256, 256, 0, stream>>>(rowE, colE, dinv, row_fill, csr_col, csr_val);

  k_lin0<<<N_NODES/16, 256, 0, stream>>>(x, W_lin, b_lin, h0);

  const __half* hin = h0;
  __half* bufs[2] = {hA, hB};
  for(int L=0; L<8; L++){
    float beta = logf(0.5f/(float)(L+1) + 1.0f);
    __half* hout = bufs[L&1];
    k_layer<<<(N_NODES+15)/16, 256, 0, stream>>>(hin, h0, row_ptr, csr_col, csr_val, dinv,
                                                 Ws + (size_t)L*4096, beta, hout);
    hin = hout;
  }
  // final h is hB (layer 7 writes bufs[1])
  k_ab<<<N_NODES/16, 256, 0, stream>>>(hB, W1, Abuf, Bbuf);
  k_edge<<<N_EDGES/64, 256, 0, stream>>>(Abuf, Bbuf, rowE, colE, b1, ln_g, ln_b, W2, b2, out);
}